// Round 1
// baseline (112.104 us; speedup 1.0000x reference)
//
#include <hip/hip_runtime.h>
#include <hip/hip_bf16.h>

// Problem constants (B=4, Tq=Tk=512, Q=K=1024, C=256)
#define M_ROWS 2048   // B*Tq = B*Tk
#define KDIM   1024
#define CDIM   256
#define TQ     512
#define TK     512

#define GBM 64        // m rows per block (gemm)
#define GBN 32        // c cols per block (gemm)
#define GBK 32        // k per stage
#define NIT (KDIM / GBK)   // 32 k-iterations
#define DEPTH 4       // register prefetch depth (covers ~900cy cold HBM / 4)

// 2*log2(e): tanh(x) = 1 - 2/(exp2(2log2e * x) + 1)
#define SCALE2LOG2E 2.8853900817779268f

typedef __attribute__((ext_vector_type(8))) short short8;
typedef __attribute__((ext_vector_type(8))) unsigned short ushort8;
typedef __attribute__((ext_vector_type(4))) float floatx4;
typedef __attribute__((ext_vector_type(2))) float f32x2;

__device__ __forceinline__ short2 cvt2(float x, float y) {
    __hip_bfloat162 h = __float22bfloat162_rn(make_float2(x, y));
    short2 r;
    __builtin_memcpy(&r, &h, sizeof(r));
    return r;
}
__device__ __forceinline__ unsigned short f2bf1(float x) {
    return (unsigned short)cvt2(x, x).x;
}
__device__ __forceinline__ float bf2f(unsigned short u) {
    return __builtin_bit_cast(float, (unsigned)u << 16);
}
__device__ __forceinline__ f32x2 splat2(float x) { return (f32x2){x, x}; }

// MFMA GEMM producing E_bf16[c][m] = bf16(exp2(S * sum_k A[m][k]*W[k][c])),
// q-side additionally prescaled by s_c = -0.5/w_c.
// A-fragment loaded DIRECTLY from global per lane (no LDS for A).
// v2 changes vs verified 110us kernel:
//  - depth-4 register prefetch (was 2): load->use distance ~4 iters covers
//    the ~900cy cold-HBM latency (L3 poisoned each harness iteration)
//  - double-buffered Ws -> ONE __syncthreads per k-iter (was 2)
//  - k-loop fully unrolled so all prefetch-slot indices are compile-time
__global__ __launch_bounds__(256) void gemm_mfma_kernel(
    const float* __restrict__ Aq, const float* __restrict__ Ak,
    const float* __restrict__ Wq, const float* __restrict__ Wk,
    const float* __restrict__ w_attn,
    unsigned short* __restrict__ Eq, unsigned short* __restrict__ Ek)
{
    __shared__ short Ws[2][GBN][GBK + 8];   // double-buffered [c][k] tiles

    const int z = blockIdx.z;
    const float* A = z ? Ak : Aq;
    const float* W = z ? Wk : Wq;
    unsigned short* E = z ? Ek : Eq;

    const int t    = threadIdx.x;
    const int lane = t & 63;
    const int wave = t >> 6;
    const int m0   = blockIdx.x * GBM;
    const int n0   = blockIdx.y * GBN;

    const int wr = t >> 3;            // W stage: k row 0..31
    const int wc = (t & 7) * 4;       // W stage: c col 0,4,..,28
    const int li = lane & 15;
    const int qd = lane >> 4;

    const int row = m0 + wave * 16 + li;        // this lane's m row
    const float* Arow = A + (size_t)row * KDIM + qd * 8;

    floatx4 acc0 = {0.f, 0.f, 0.f, 0.f};   // c half 0 (c = n0 + qd*4+r)
    floatx4 acc1 = {0.f, 0.f, 0.f, 0.f};   // c half 1 (+16)

    // depth-4 prefetch: slot d holds data for iteration (it ≡ d mod 4)
    float4 pa0[DEPTH], pa1[DEPTH], pw[DEPTH];
    #pragma unroll
    for (int d = 0; d < DEPTH; ++d) {
        pa0[d] = *(const float4*)&Arow[d * GBK];
        pa1[d] = *(const float4*)&Arow[d * GBK + 4];
        pw[d]  = *(const float4*)&W[(size_t)(d * GBK + wr) * CDIM + n0 + wc];
    }

    {   // prologue: stage iteration 0's W tile into buffer 0
        short2 u0 = cvt2(pw[0].x, pw[0].y), u1 = cvt2(pw[0].z, pw[0].w);
        Ws[0][wc + 0][wr] = u0.x;
        Ws[0][wc + 1][wr] = u0.y;
        Ws[0][wc + 2][wr] = u1.x;
        Ws[0][wc + 3][wr] = u1.y;
    }
    __syncthreads();

    #pragma unroll
    for (int it = 0; it < NIT; ++it) {
        const int buf = it & 1;
        const int s   = it & 3;
        // A fragment for this iter from prefetched regs
        short2 p0 = cvt2(pa0[s].x, pa0[s].y), p1 = cvt2(pa0[s].z, pa0[s].w);
        short2 p2 = cvt2(pa1[s].x, pa1[s].y), p3 = cvt2(pa1[s].z, pa1[s].w);
        short8 bv = { p0.x, p0.y, p1.x, p1.y, p2.x, p2.y, p3.x, p3.y };
        short8 af0 = *(const short8*)&Ws[buf][li][qd * 8];
        short8 af1 = *(const short8*)&Ws[buf][16 + li][qd * 8];
        acc0 = __builtin_amdgcn_mfma_f32_16x16x32_bf16(af0, bv, acc0, 0, 0, 0);
        acc1 = __builtin_amdgcn_mfma_f32_16x16x32_bf16(af1, bv, acc1, 0, 0, 0);
        if (it + 1 < NIT) {           // stage NEXT iter's W tile into other buf
            const int ns = (it + 1) & 3;
            short2 u0 = cvt2(pw[ns].x, pw[ns].y), u1 = cvt2(pw[ns].z, pw[ns].w);
            Ws[buf ^ 1][wc + 0][wr] = u0.x;
            Ws[buf ^ 1][wc + 1][wr] = u0.y;
            Ws[buf ^ 1][wc + 2][wr] = u1.x;
            Ws[buf ^ 1][wc + 3][wr] = u1.y;
        }
        if (it + DEPTH < NIT) {       // refill slot s (just consumed)
            const int k0 = (it + DEPTH) * GBK;
            pa0[s] = *(const float4*)&Arow[k0];
            pa1[s] = *(const float4*)&Arow[k0 + 4];
            pw[s]  = *(const float4*)&W[(size_t)(k0 + wr) * CDIM + n0 + wc];
        }
        __syncthreads();              // next-iter Ws ready; prev reads done
    }

    #pragma unroll
    for (int r = 0; r < 4; ++r) {
        const int c0 = n0 + qd * 4 + r;
        const int c1 = c0 + 16;
        float s0 = z ? 1.0f : (-0.5f / w_attn[c0]);
        float s1 = z ? 1.0f : (-0.5f / w_attn[c1]);
        float v0 = __builtin_amdgcn_exp2f(acc0[r] * SCALE2LOG2E) * s0;
        float v1 = __builtin_amdgcn_exp2f(acc1[r] * SCALE2LOG2E) * s1;
        E[(size_t)c0 * M_ROWS + row] = f2bf1(v0);
        E[(size_t)c1 * M_ROWS + row] = f2bf1(v1);
    }
}

// scores[b][q][k] = (b_attn + sum_c w_c) + sum_c rcp(f_c),
//   f_c = fma(Eqs[c][q], Ek[c][k], s_c),  Eqs = s_c*e^{2 q2ctx}, Ek = e^{2 k2ctx}
// 4-way pairing: 1/f1+1/f2+1/f3+1/f4 = ((f1+f2)f3f4+(f3+f4)f1f2)*rcp(f1f2f3f4)
// (identical consecutive-4c grouping as the verified kernel).
// v2 structure: 4q x 4k register blocking per thread (halves LDS bytes/term),
// the 256-c contraction split across the block's 4 waves (wave w owns
// c in [64w, 64w+64)) so wave-parallelism stays at 4096 waves, full 256x32
// f32 staging done ONCE (2 barriers total), then a conflict-free LDS
// reduction of the 4 wave-partials (red aliases the staging buffer).
__global__ __launch_bounds__(256) void bahdanau_kernel(
    const unsigned short* __restrict__ Eqs, const unsigned short* __restrict__ Ek,
    const float* __restrict__ w_attn, const float* __restrict__ b_attn,
    float* __restrict__ out)
{
    __shared__ union SMem {
        struct { float q[CDIM][36]; float k[CDIM][36]; } s;  // 73,728 B
        float red[16][4][64];                                // 16,384 B (aliased)
    } sm;
    __shared__ __align__(16) float sl[CDIM];  // s_c = -0.5/w_c
    __shared__ float partial[4];              // per-wave w sums

    const int t    = threadIdx.x;
    const int b    = blockIdx.z;
    const int q0g  = blockIdx.x * 32;
    const int k0g  = blockIdx.y * 32;
    const int gq   = b * TQ + q0g;
    const int gk   = b * TK + k0g;
    const int wave = t >> 6;
    const int tl   = t & 63;
    const int q0   = (tl >> 3) * 4;   // this lane's 4 q rows
    const int k0   = (tl & 7) * 4;    // this lane's 4 k cols

    {   // prologue: s_c and sum(w); CDIM == blockDim.x == 256
        float wv = w_attn[t];
        sl[t] = -0.5f / wv;
        float sum = wv;
        #pragma unroll
        for (int o = 32; o >= 1; o >>= 1) sum += __shfl_down(sum, o);
        if ((t & 63) == 0) partial[t >> 6] = sum;
    }

    // ---- stage full 256c x 32q + 256c x 32k tiles, bf16 -> f32, once ----
    const int sr = t >> 2;            // c row within pass (0..63)
    const int sc = (t & 3) * 8;       // 8-value chunk
    ushort8 qv[4], kv[4];
    #pragma unroll
    for (int p = 0; p < 4; ++p) {     // issue all 8 loads before any LDS write
        qv[p] = *(const ushort8*)&Eqs[(size_t)(p * 64 + sr) * M_ROWS + gq + sc];
        kv[p] = *(const ushort8*)&Ek [(size_t)(p * 64 + sr) * M_ROWS + gk + sc];
    }
    #pragma unroll
    for (int p = 0; p < 4; ++p) {
        const int r = p * 64 + sr;
        *(float4*)&sm.s.q[r][sc]     = make_float4(bf2f(qv[p][0]), bf2f(qv[p][1]), bf2f(qv[p][2]), bf2f(qv[p][3]));
        *(float4*)&sm.s.q[r][sc + 4] = make_float4(bf2f(qv[p][4]), bf2f(qv[p][5]), bf2f(qv[p][6]), bf2f(qv[p][7]));
        *(float4*)&sm.s.k[r][sc]     = make_float4(bf2f(kv[p][0]), bf2f(kv[p][1]), bf2f(kv[p][2]), bf2f(kv[p][3]));
        *(float4*)&sm.s.k[r][sc + 4] = make_float4(bf2f(kv[p][4]), bf2f(kv[p][5]), bf2f(kv[p][6]), bf2f(kv[p][7]));
    }
    __syncthreads();

    // ---- compute: wave handles c chunk [wave*64, wave*64+64) ----
    f32x2 acc[4][2];
    #pragma unroll
    for (int qi = 0; qi < 4; ++qi) {
        acc[qi][0] = (f32x2){0.f, 0.f};
        acc[qi][1] = (f32x2){0.f, 0.f};
    }
    const int cb = wave * 64;
    #pragma unroll 2
    for (int cc = 0; cc < 64; cc += 4) {
        float4 s4 = *(const float4*)&sl[cb + cc];
        f32x2 qa[4][2], ka[4][2];
        #pragma unroll
        for (int j = 0; j < 4; ++j) {
            qa[j][0] = *(const f32x2*)&sm.s.q[cb + cc + j][q0];
            qa[j][1] = *(const f32x2*)&sm.s.q[cb + cc + j][q0 + 2];
            ka[j][0] = *(const f32x2*)&sm.s.k[cb + cc + j][k0];
            ka[j][1] = *(const f32x2*)&sm.s.k[cb + cc + j][k0 + 2];
        }
        #pragma unroll
        for (int qi = 0; qi < 4; ++qi) {
            const float qw0 = qa[0][qi >> 1][qi & 1];
            const float qw1 = qa[1][qi >> 1][qi & 1];
            const float qw2 = qa[2][qi >> 1][qi & 1];
            const float qw3 = qa[3][qi >> 1][qi & 1];
            #pragma unroll
            for (int kp = 0; kp < 2; ++kp) {
                f32x2 f1 = __builtin_elementwise_fma(splat2(qw0), ka[0][kp], splat2(s4.x));
                f32x2 f2 = __builtin_elementwise_fma(splat2(qw1), ka[1][kp], splat2(s4.y));
                f32x2 f3 = __builtin_elementwise_fma(splat2(qw2), ka[2][kp], splat2(s4.z));
                f32x2 f4 = __builtin_elementwise_fma(splat2(qw3), ka[3][kp], splat2(s4.w));
                f32x2 p12 = f1 * f2, p34 = f3 * f4;
                f32x2 s12 = f1 + f2, s34 = f3 + f4;
                f32x2 num = __builtin_elementwise_fma(s12, p34, s34 * p12);
                f32x2 den = p12 * p34;
                f32x2 r = {__builtin_amdgcn_rcpf(den.x), __builtin_amdgcn_rcpf(den.y)};
                acc[qi][kp] = __builtin_elementwise_fma(num, r, acc[qi][kp]);
            }
        }
    }

    // ---- cross-wave reduction (red aliases staging buffer) ----
    __syncthreads();                  // all waves done reading sm.s
    #pragma unroll
    for (int qi = 0; qi < 4; ++qi) {
        #pragma unroll
        for (int kp = 0; kp < 2; ++kp) {
            sm.red[qi * 4 + kp * 2 + 0][wave][tl] = acc[qi][kp].x;
            sm.red[qi * 4 + kp * 2 + 1][wave][tl] = acc[qi][kp].y;
        }
    }
    __syncthreads();

    const float bias2 = *b_attn + partial[0] + partial[1] + partial[2] + partial[3];
    // thread t finalizes lane L's q-row i (4 outputs)
    const int L  = t & 63;
    const int i  = t >> 6;
    const int qr = (L >> 3) * 4 + i;
    const int kc = (L & 7) * 4;
    float4 v;
    #pragma unroll
    for (int j = 0; j < 4; ++j) {
        float s = sm.red[i * 4 + j][0][L] + sm.red[i * 4 + j][1][L]
                + sm.red[i * 4 + j][2][L] + sm.red[i * 4 + j][3][L];
        (&v.x)[j] = s + bias2;
    }
    *(float4*)&out[((size_t)b * TQ + q0g + qr) * TK + k0g + kc] = v;
}

extern "C" void kernel_launch(void* const* d_in, const int* in_sizes, int n_in,
                              void* d_out, int out_size, void* d_ws, size_t ws_size,
                              hipStream_t stream) {
    const float* query  = (const float*)d_in[0];
    const float* key    = (const float*)d_in[1];
    const float* Wq     = (const float*)d_in[2];
    const float* Wk     = (const float*)d_in[3];
    const float* w_attn = (const float*)d_in[4];
    const float* b_attn = (const float*)d_in[5];
    float* out = (float*)d_out;

    unsigned short* Eqs = (unsigned short*)d_ws;      // 256 x 2048 bf16 = 1 MB
    unsigned short* Ek  = Eqs + (size_t)CDIM * M_ROWS;// 256 x 2048 bf16 = 1 MB

    dim3 gemm_grid(M_ROWS / GBM, CDIM / GBN, 2);   // 32 x 8 x 2 = 512 blocks
    gemm_mfma_kernel<<<gemm_grid, 256, 0, stream>>>(query, key, Wq, Wk, w_attn, Eqs, Ek);

    dim3 main_grid(TQ / 32, TK / 32, 4);           // 16 x 16 x 4 = 1024 blocks
    bahdanau_kernel<<<main_grid, 256, 0, stream>>>(Eqs, Ek, w_attn, b_attn, out);
}

// Round 2
// 110.402 us; speedup vs baseline: 1.0154x; 1.0154x over previous
//
#include <hip/hip_runtime.h>
#include <hip/hip_bf16.h>

// Problem constants (B=4, Tq=Tk=512, Q=K=1024, C=256)
#define M_ROWS 2048   // B*Tq = B*Tk
#define KDIM   1024
#define CDIM   256
#define TQ     512
#define TK     512

#define GBM 64        // m rows per block (gemm)
#define GBN 32        // c cols per block (gemm)
#define GBK 32        // k per stage

// 2*log2(e): tanh(x) = 1 - 2/(exp2(2log2e * x) + 1)
#define SCALE2LOG2E 2.8853900817779268f

typedef __attribute__((ext_vector_type(8))) short short8;
typedef __attribute__((ext_vector_type(8))) unsigned short ushort8;
typedef __attribute__((ext_vector_type(4))) float floatx4;
typedef __attribute__((ext_vector_type(2))) float f32x2;

__device__ __forceinline__ short2 cvt2(float x, float y) {
    __hip_bfloat162 h = __float22bfloat162_rn(make_float2(x, y));
    short2 r;
    __builtin_memcpy(&r, &h, sizeof(r));
    return r;
}
__device__ __forceinline__ unsigned short f2bf1(float x) {
    return (unsigned short)cvt2(x, x).x;
}
__device__ __forceinline__ float bf2f(unsigned short u) {
    return __builtin_bit_cast(float, (unsigned)u << 16);
}
__device__ __forceinline__ f32x2 splat2(float x) { return (f32x2){x, x}; }

// MFMA GEMM producing E_bf16[c][m] = bf16(exp2(S * sum_k A[m][k]*W[k][c])),
// q-side additionally prescaled by s_c = -0.5/w_c.
// (Reverted to the verified round-0 form: depth-2 prefetch, 2 barriers/iter.
//  Depth-4 + single-barrier was measured neutral -> gemm is not latency-bound;
//  its ~6-8us is ds_read+MFMA+barrier critical path at grid-limited 2 blk/CU.)
__global__ __launch_bounds__(256) void gemm_mfma_kernel(
    const float* __restrict__ Aq, const float* __restrict__ Ak,
    const float* __restrict__ Wq, const float* __restrict__ Wk,
    const float* __restrict__ w_attn,
    unsigned short* __restrict__ Eq, unsigned short* __restrict__ Ek)
{
    __shared__ short Ws[GBN][GBK + 8];   // [c][k] 32x40 shorts (80B rows)

    const int z = blockIdx.z;
    const float* A = z ? Ak : Aq;
    const float* W = z ? Wk : Wq;
    unsigned short* E = z ? Ek : Eq;

    const int t    = threadIdx.x;
    const int lane = t & 63;
    const int wave = t >> 6;
    const int m0   = blockIdx.x * GBM;
    const int n0   = blockIdx.y * GBN;

    const int wr = t >> 3;            // W stage: k row 0..31
    const int wc = (t & 7) * 4;       // W stage: c col 0,4,..,28
    const int li = lane & 15;
    const int qd = lane >> 4;

    const int row = m0 + wave * 16 + li;        // this lane's m row
    const float* Arow = A + (size_t)row * KDIM + qd * 8;

    floatx4 acc0 = {0.f, 0.f, 0.f, 0.f};   // c half 0 (c = n0 + qd*4+r)
    floatx4 acc1 = {0.f, 0.f, 0.f, 0.f};   // c half 1 (+16)

    // depth-2 prefetch
    float4 pa0[2], pa1[2], pw[2];
    pa0[0] = *(const float4*)&Arow[0];
    pa1[0] = *(const float4*)&Arow[4];
    pw[0]  = *(const float4*)&W[(size_t)wr * CDIM + n0 + wc];
    pa0[1] = *(const float4*)&Arow[GBK];
    pa1[1] = *(const float4*)&Arow[GBK + 4];
    pw[1]  = *(const float4*)&W[(size_t)(GBK + wr) * CDIM + n0 + wc];

    for (int it = 0; it < KDIM / GBK; ++it) {
        const int s = it & 1;
        __syncthreads();                       // prev-iter Ws reads done
        short2 u0 = cvt2(pw[s].x, pw[s].y), u1 = cvt2(pw[s].z, pw[s].w);
        Ws[wc + 0][wr] = u0.x;
        Ws[wc + 1][wr] = u0.y;
        Ws[wc + 2][wr] = u1.x;
        Ws[wc + 3][wr] = u1.y;
        short2 p0 = cvt2(pa0[s].x, pa0[s].y), p1 = cvt2(pa0[s].z, pa0[s].w);
        short2 p2 = cvt2(pa1[s].x, pa1[s].y), p3 = cvt2(pa1[s].z, pa1[s].w);
        short8 bv = { p0.x, p0.y, p1.x, p1.y, p2.x, p2.y, p3.x, p3.y };
        __syncthreads();                       // Ws ready
        if (it + 2 < KDIM / GBK) {             // refill slot s (just consumed)
            const int k0 = (it + 2) * GBK;
            pa0[s] = *(const float4*)&Arow[k0];
            pa1[s] = *(const float4*)&Arow[k0 + 4];
            pw[s]  = *(const float4*)&W[(size_t)(k0 + wr) * CDIM + n0 + wc];
        }
        short8 af0 = *(const short8*)&Ws[li][qd * 8];
        short8 af1 = *(const short8*)&Ws[16 + li][qd * 8];
        acc0 = __builtin_amdgcn_mfma_f32_16x16x32_bf16(af0, bv, acc0, 0, 0, 0);
        acc1 = __builtin_amdgcn_mfma_f32_16x16x32_bf16(af1, bv, acc1, 0, 0, 0);
    }

    #pragma unroll
    for (int r = 0; r < 4; ++r) {
        const int c0 = n0 + qd * 4 + r;
        const int c1 = c0 + 16;
        float s0 = z ? 1.0f : (-0.5f / w_attn[c0]);
        float s1 = z ? 1.0f : (-0.5f / w_attn[c1]);
        float v0 = __builtin_amdgcn_exp2f(acc0[r] * SCALE2LOG2E) * s0;
        float v1 = __builtin_amdgcn_exp2f(acc1[r] * SCALE2LOG2E) * s1;
        E[(size_t)c0 * M_ROWS + row] = f2bf1(v0);
        E[(size_t)c1 * M_ROWS + row] = f2bf1(v1);
    }
}

// scores[b][q][k] = (b_attn + sum_c w_c) + sum_c rcp(f_c),
//   f_c = fma(Eqs[c][q], Ek[c][k], s_c),  Eqs = s_c*e^{2 q2ctx}, Ek = e^{2 k2ctx}
// 4-way pairing: 1/f1+1/f2+1/f3+1/f4 = ((f1+f2)f3f4+(f3+f4)f1f2)*rcp(f1f2f3f4)
// (identical consecutive-4c grouping as the verified kernel).
// v3: keeps v2's 4qx4k register blocking (0.25 LDS-b64/term, half of v1) and
// wave-split-C contraction, but stages C in TWO 128-row phases so the staging
// buffer is 36.9KB (was 73.7KB) -> LDS ~38KB/block -> 4 blocks/CU restored
// (v2's hidden regression: 75KB -> 2 blocks/CU = 2 waves/SIMD ate the gain).
// __launch_bounds__(256,4) caps VGPR at 128 to hold 4 blocks/CU.
__global__ __launch_bounds__(256, 4) void bahdanau_kernel(
    const unsigned short* __restrict__ Eqs, const unsigned short* __restrict__ Ek,
    const float* __restrict__ w_attn, const float* __restrict__ b_attn,
    float* __restrict__ out)
{
    __shared__ union SMem {
        struct { float q[128][36]; float k[128][36]; } s;  // 36,864 B
        float red[16][4][64];                              // 16,384 B (aliased)
    } sm;
    __shared__ __align__(16) float sl[CDIM];  // s_c = -0.5/w_c
    __shared__ float partial[4];              // per-wave w sums

    const int t    = threadIdx.x;
    const int b    = blockIdx.z;
    const int q0g  = blockIdx.x * 32;
    const int k0g  = blockIdx.y * 32;
    const int gq   = b * TQ + q0g;
    const int gk   = b * TK + k0g;
    const int wave = t >> 6;
    const int tl   = t & 63;
    const int q0   = (tl >> 3) * 4;   // this lane's 4 q rows
    const int k0   = (tl & 7) * 4;    // this lane's 4 k cols

    {   // prologue: s_c and sum(w); CDIM == blockDim.x == 256
        float wv = w_attn[t];
        sl[t] = -0.5f / wv;
        float sum = wv;
        #pragma unroll
        for (int o = 32; o >= 1; o >>= 1) sum += __shfl_down(sum, o);
        if ((t & 63) == 0) partial[t >> 6] = sum;
    }

    // staging role: thread t handles c-row sr (phase-local), 16-col half sc
    const int sr = t >> 1;            // 0..127
    const int sc = (t & 1) * 16;      // 0 or 16

    // phase-0 global loads (32B contiguous per side per thread, as 2x ushort8)
    ushort8 qv[2], kv[2];
    qv[0] = *(const ushort8*)&Eqs[(size_t)sr * M_ROWS + gq + sc];
    qv[1] = *(const ushort8*)&Eqs[(size_t)sr * M_ROWS + gq + sc + 8];
    kv[0] = *(const ushort8*)&Ek [(size_t)sr * M_ROWS + gk + sc];
    kv[1] = *(const ushort8*)&Ek [(size_t)sr * M_ROWS + gk + sc + 8];

    f32x2 acc[4][2];
    #pragma unroll
    for (int qi = 0; qi < 4; ++qi) {
        acc[qi][0] = (f32x2){0.f, 0.f};
        acc[qi][1] = (f32x2){0.f, 0.f};
    }

    #pragma unroll
    for (int ph = 0; ph < 2; ++ph) {
        // write staged regs -> LDS (bf16 -> f32)
        *(float4*)&sm.s.q[sr][sc]      = make_float4(bf2f(qv[0][0]), bf2f(qv[0][1]), bf2f(qv[0][2]), bf2f(qv[0][3]));
        *(float4*)&sm.s.q[sr][sc + 4]  = make_float4(bf2f(qv[0][4]), bf2f(qv[0][5]), bf2f(qv[0][6]), bf2f(qv[0][7]));
        *(float4*)&sm.s.q[sr][sc + 8]  = make_float4(bf2f(qv[1][0]), bf2f(qv[1][1]), bf2f(qv[1][2]), bf2f(qv[1][3]));
        *(float4*)&sm.s.q[sr][sc + 12] = make_float4(bf2f(qv[1][4]), bf2f(qv[1][5]), bf2f(qv[1][6]), bf2f(qv[1][7]));
        *(float4*)&sm.s.k[sr][sc]      = make_float4(bf2f(kv[0][0]), bf2f(kv[0][1]), bf2f(kv[0][2]), bf2f(kv[0][3]));
        *(float4*)&sm.s.k[sr][sc + 4]  = make_float4(bf2f(kv[0][4]), bf2f(kv[0][5]), bf2f(kv[0][6]), bf2f(kv[0][7]));
        *(float4*)&sm.s.k[sr][sc + 8]  = make_float4(bf2f(kv[1][0]), bf2f(kv[1][1]), bf2f(kv[1][2]), bf2f(kv[1][3]));
        *(float4*)&sm.s.k[sr][sc + 12] = make_float4(bf2f(kv[1][4]), bf2f(kv[1][5]), bf2f(kv[1][6]), bf2f(kv[1][7]));
        __syncthreads();              // tile staged

        if (ph == 0) {                // prefetch phase-1 rows (hides under compute)
            qv[0] = *(const ushort8*)&Eqs[(size_t)(128 + sr) * M_ROWS + gq + sc];
            qv[1] = *(const ushort8*)&Eqs[(size_t)(128 + sr) * M_ROWS + gq + sc + 8];
            kv[0] = *(const ushort8*)&Ek [(size_t)(128 + sr) * M_ROWS + gk + sc];
            kv[1] = *(const ushort8*)&Ek [(size_t)(128 + sr) * M_ROWS + gk + sc + 8];
        }

        // wave handles phase-local c chunk [wave*32, wave*32+32)
        const int cb = wave * 32;
        #pragma unroll 2
        for (int cc = 0; cc < 32; cc += 4) {
            float4 s4 = *(const float4*)&sl[ph * 128 + cb + cc];
            f32x2 qa[4][2], ka[4][2];
            #pragma unroll
            for (int j = 0; j < 4; ++j) {
                qa[j][0] = *(const f32x2*)&sm.s.q[cb + cc + j][q0];
                qa[j][1] = *(const f32x2*)&sm.s.q[cb + cc + j][q0 + 2];
                ka[j][0] = *(const f32x2*)&sm.s.k[cb + cc + j][k0];
                ka[j][1] = *(const f32x2*)&sm.s.k[cb + cc + j][k0 + 2];
            }
            #pragma unroll
            for (int qi = 0; qi < 4; ++qi) {
                const float qw0 = qa[0][qi >> 1][qi & 1];
                const float qw1 = qa[1][qi >> 1][qi & 1];
                const float qw2 = qa[2][qi >> 1][qi & 1];
                const float qw3 = qa[3][qi >> 1][qi & 1];
                #pragma unroll
                for (int kp = 0; kp < 2; ++kp) {
                    f32x2 f1 = __builtin_elementwise_fma(splat2(qw0), ka[0][kp], splat2(s4.x));
                    f32x2 f2 = __builtin_elementwise_fma(splat2(qw1), ka[1][kp], splat2(s4.y));
                    f32x2 f3 = __builtin_elementwise_fma(splat2(qw2), ka[2][kp], splat2(s4.z));
                    f32x2 f4 = __builtin_elementwise_fma(splat2(qw3), ka[3][kp], splat2(s4.w));
                    f32x2 p12 = f1 * f2, p34 = f3 * f4;
                    f32x2 s12 = f1 + f2, s34 = f3 + f4;
                    f32x2 num = __builtin_elementwise_fma(s12, p34, s34 * p12);
                    f32x2 den = p12 * p34;
                    f32x2 r = {__builtin_amdgcn_rcpf(den.x), __builtin_amdgcn_rcpf(den.y)};
                    acc[qi][kp] = __builtin_elementwise_fma(num, r, acc[qi][kp]);
                }
            }
        }
        __syncthreads();              // compute done before overwrite / red alias
    }

    // ---- cross-wave reduction (red aliases staging buffer) ----
    #pragma unroll
    for (int qi = 0; qi < 4; ++qi) {
        #pragma unroll
        for (int kp = 0; kp < 2; ++kp) {
            sm.red[qi * 4 + kp * 2 + 0][wave][tl] = acc[qi][kp].x;
            sm.red[qi * 4 + kp * 2 + 1][wave][tl] = acc[qi][kp].y;
        }
    }
    __syncthreads();

    const float bias2 = *b_attn + partial[0] + partial[1] + partial[2] + partial[3];
    // thread t finalizes lane L's q-row i (4 outputs)
    const int L  = t & 63;
    const int i  = t >> 6;
    const int qr = (L >> 3) * 4 + i;
    const int kc = (L & 7) * 4;
    float4 v;
    #pragma unroll
    for (int j = 0; j < 4; ++j) {
        float s = sm.red[i * 4 + j][0][L] + sm.red[i * 4 + j][1][L]
                + sm.red[i * 4 + j][2][L] + sm.red[i * 4 + j][3][L];
        (&v.x)[j] = s + bias2;
    }
    *(float4*)&out[((size_t)b * TQ + q0g + qr) * TK + k0g + kc] = v;
}

extern "C" void kernel_launch(void* const* d_in, const int* in_sizes, int n_in,
                              void* d_out, int out_size, void* d_ws, size_t ws_size,
                              hipStream_t stream) {
    const float* query  = (const float*)d_in[0];
    const float* key    = (const float*)d_in[1];
    const float* Wq     = (const float*)d_in[2];
    const float* Wk     = (const float*)d_in[3];
    const float* w_attn = (const float*)d_in[4];
    const float* b_attn = (const float*)d_in[5];
    float* out = (float*)d_out;

    unsigned short* Eqs = (unsigned short*)d_ws;      // 256 x 2048 bf16 = 1 MB
    unsigned short* Ek  = Eqs + (size_t)CDIM * M_ROWS;// 256 x 2048 bf16 = 1 MB

    dim3 gemm_grid(M_ROWS / GBM, CDIM / GBN, 2);   // 32 x 8 x 2 = 512 blocks
    gemm_mfma_kernel<<<gemm_grid, 256, 0, stream>>>(query, key, Wq, Wk, w_attn, Eqs, Ek);

    dim3 main_grid(TQ / 32, TK / 32, 4);           // 16 x 16 x 4 = 1024 blocks
    bahdanau_kernel<<<main_grid, 256, 0, stream>>>(Eqs, Ek, w_attn, b_attn, out);
}